// Round 1
// baseline (50324.643 us; speedup 1.0000x reference)
//
#include <hip/hip_runtime.h>
#include <stdint.h>

typedef __attribute__((ext_vector_type(8))) short short8;
typedef __attribute__((ext_vector_type(4))) float f32x4;
typedef unsigned short u16;
typedef unsigned int u32;

__device__ __forceinline__ float bf2f(u16 v) {
    u32 t = ((u32)v) << 16; float f; __builtin_memcpy(&f, &t, 4); return f;
}
__device__ __forceinline__ u16 f2bf(float f) {
    u32 t; __builtin_memcpy(&t, &f, 4);
    return (u16)((t + 0x7FFFu + ((t >> 16) & 1u)) >> 16);
}

// ---------------- cast x (f32 -> bf16), 4 elems/thread ----------------
__global__ __launch_bounds__(256) void cast_f32_bf16(const float* __restrict__ in,
                                                     u16* __restrict__ out, int n4) {
    int i = blockIdx.x * 256 + threadIdx.x;
    if (i < n4) {
        float4 v = ((const float4*)in)[i];
        uint2 pk;
        pk.x = (u32)f2bf(v.x) | ((u32)f2bf(v.y) << 16);
        pk.y = (u32)f2bf(v.z) | ((u32)f2bf(v.w) << 16);
        ((uint2*)out)[i] = pk;
    }
}

// ---------- transpose + cast: in f32 [K][2048] -> out bf16 [2048][K] ----------
__global__ void transpose_cast(const float* __restrict__ in, u16* __restrict__ out, int K) {
    __shared__ float tile[32][33];
    int n0 = blockIdx.x * 32, k0 = blockIdx.y * 32;
    int tx = threadIdx.x, ty = threadIdx.y; // block (32,8)
    for (int i = 0; i < 4; i++)
        tile[ty + i * 8][tx] = in[(size_t)(k0 + ty + i * 8) * 2048 + n0 + tx];
    __syncthreads();
    for (int i = 0; i < 4; i++)
        out[(size_t)(n0 + ty + i * 8) * K + k0 + tx] = f2bf(tile[tx][ty + i * 8]);
}

// ---------------- bf16 MFMA GEMM: C[M,N] = A[M,K] @ Bt[N,K]^T + bias ----------------
// A row-major bf16, Bt = B^T row-major bf16, C bf16. 128x128 tile, BK=32, 256 thr.
__global__ __launch_bounds__(256) void gemm_bt(const u16* __restrict__ A,
                                               const u16* __restrict__ Bt,
                                               const float* __restrict__ bias,
                                               u16* __restrict__ C,
                                               int M, int N, int K) {
    __shared__ u16 As[128 * 40];
    __shared__ u16 Bs[128 * 40];
    int bm = blockIdx.y, bn = blockIdx.x;
    int tid = threadIdx.x, lane = tid & 63, wv = tid >> 6;
    int n = lane & 15, q = lane >> 4;
    int wm = wv & 1, wn = wv >> 1;
    f32x4 acc[4][4] = {};
    int rowA0 = bm * 128, rowB0 = bn * 128;
    for (int kt = 0; kt < K; kt += 32) {
        uint4 va[2], vb[2];
        #pragma unroll
        for (int s = 0; s < 2; s++) {
            int slot = tid + s * 256;
            int row = slot >> 2, ko = (slot & 3) * 8;
            va[s] = *(const uint4*)(A + (size_t)(rowA0 + row) * K + kt + ko);
            vb[s] = *(const uint4*)(Bt + (size_t)(rowB0 + row) * K + kt + ko);
        }
        __syncthreads();
        #pragma unroll
        for (int s = 0; s < 2; s++) {
            int slot = tid + s * 256;
            int row = slot >> 2, ko = (slot & 3) * 8;
            *(uint4*)(As + row * 40 + ko) = va[s];
            *(uint4*)(Bs + row * 40 + ko) = vb[s];
        }
        __syncthreads();
        short8 af[4], bfr[4];
        #pragma unroll
        for (int i = 0; i < 4; i++)
            af[i] = *(const short8*)(As + (wm * 64 + i * 16 + n) * 40 + q * 8);
        #pragma unroll
        for (int j = 0; j < 4; j++)
            bfr[j] = *(const short8*)(Bs + (wn * 64 + j * 16 + n) * 40 + q * 8);
        #pragma unroll
        for (int i = 0; i < 4; i++)
            #pragma unroll
            for (int j = 0; j < 4; j++)
                acc[i][j] = __builtin_amdgcn_mfma_f32_16x16x32_bf16(af[i], bfr[j], acc[i][j], 0, 0, 0);
    }
    #pragma unroll
    for (int j = 0; j < 4; j++) {
        int col = bn * 128 + wn * 64 + j * 16 + n;
        float bv = bias[col];
        #pragma unroll
        for (int i = 0; i < 4; i++) {
            int row = bm * 128 + wm * 64 + i * 16 + q * 4;
            #pragma unroll
            for (int r = 0; r < 4; r++)
                C[(size_t)(row + r) * N + col] = f2bf(acc[i][j][r] + bv);
        }
    }
}

// ---------------- persistent LSTM recurrence ----------------
// 256 WGs x 256 thr, 1 WG/CU (LDS-forced). WG (mt,ntb): batches [mt*16,+16),
// j-block [ntb*8,+8) -> 32 z-cols {g*512 + j}. U frags register-resident.
// waves: wv = kh*2 + nt ; nt: Ntile (0: gates i,f ; 1: g,o), kh: K-half.
__global__ __launch_bounds__(256) void lstm_rec(const u16* __restrict__ xw,
                                                const u16* __restrict__ Ut,
                                                u16* __restrict__ hbuf,
                                                u32* __restrict__ ctr,
                                                u16* __restrict__ h1out,
                                                float* __restrict__ fout,
                                                int reverse) {
    __shared__ u16 hs[16 * 520];          // staged h tile (padded rows)
    __shared__ float part[2][16 * 17];    // K-partial / gate exchange tiles
    __shared__ char forcer[80000];        // force 1 block/CU for residency
    if (blockIdx.x > 1000000u) ((volatile char*)forcer)[threadIdx.x] = 1;

    int wg = blockIdx.x;
    int mt = wg >> 6;        // batch group 0..3
    int ntb = wg & 63;       // j block 0..63
    int jbase = ntb * 8;
    int b0 = mt * 16;
    int tid = threadIdx.x, lane = tid & 63, wv = tid >> 6;
    int nt = wv & 1, kh = wv >> 1;
    int n = lane & 15, q = lane >> 4;
    int lc = nt * 16 + n;
    int gcol = (lc >> 3) * 512 + jbase + (lc & 7); // global z column

    // register-resident B (U^T) fragments: 8 K-steps of 32 for this K-half
    short8 Breg[8];
    #pragma unroll
    for (int s = 0; s < 8; s++) {
        int k = (kh * 8 + s) * 32 + q * 8;
        Breg[s] = *(const short8*)(Ut + (size_t)gcol * 512 + k);
    }
    float cst[4] = {0.f, 0.f, 0.f, 0.f};
    u32* ctrg = ctr + mt * 512;

    for (int t = 0; t < 512; t++) {
        int tt = reverse ? (511 - t) : t;
        int par = t & 1;
        const u16* hb = hbuf + par * (64 * 512);
        #pragma unroll
        for (int s = 0; s < 4; s++) {
            int slot = tid + s * 256;                 // 0..1023
            int row = slot >> 6, off = (slot & 63) * 8;
            uint4 v = *(const uint4*)(hb + (b0 + row) * 512 + off);
            *(uint4*)(hs + row * 520 + off) = v;
        }
        __syncthreads();

        f32x4 acc = {0.f, 0.f, 0.f, 0.f};
        if (kh == 0) {
            #pragma unroll
            for (int r = 0; r < 4; r++)
                acc[r] = bf2f(xw[(size_t)((b0 + q * 4 + r) * 512 + tt) * 2048 + gcol]);
        }
        #pragma unroll
        for (int s = 0; s < 8; s++) {
            int k = (kh * 8 + s) * 32 + q * 8;
            short8 a = *(const short8*)(hs + n * 520 + k);
            acc = __builtin_amdgcn_mfma_f32_16x16x32_bf16(a, Breg[s], acc, 0, 0, 0);
        }
        if (kh == 1) {
            #pragma unroll
            for (int r = 0; r < 4; r++) part[nt][(q * 4 + r) * 17 + n] = acc[r];
        }
        __syncthreads();
        if (kh == 0) {
            #pragma unroll
            for (int r = 0; r < 4; r++) acc[r] += part[nt][(q * 4 + r) * 17 + n];
        }
        if (wv == 1) { // full z for gates g,o -> publish
            #pragma unroll
            for (int r = 0; r < 4; r++) part[1][(q * 4 + r) * 17 + n] = acc[r];
        }
        __syncthreads();
        if (wv == 0) {
            float zif[4], zgo[4];
            #pragma unroll
            for (int r = 0; r < 4; r++) {
                zif[r] = acc[r];
                zgo[r] = part[1][(q * 4 + r) * 17 + n];
            }
            #pragma unroll
            for (int r = 0; r < 4; r++) {
                float oif = __shfl_xor(zif[r], 8);
                float ogo = __shfl_xor(zgo[r], 8);
                float zi = (n < 8) ? zif[r] : oif;
                float zf = (n < 8) ? oif : zif[r];
                float zg = (n < 8) ? zgo[r] : ogo;
                float zo = (n < 8) ? ogo : zgo[r];
                if (n < 8) {
                    float si = 1.f / (1.f + __expf(-zi));
                    float sf = 1.f / (1.f + __expf(-zf));
                    float so = 1.f / (1.f + __expf(-zo));
                    float g = zg > 0.f ? zg : 0.f;
                    float cn = sf * cst[r] + si * g;
                    cst[r] = cn;
                    float h = so * (cn > 0.f ? cn : 0.f);
                    int b = b0 + q * 4 + r;
                    int j = jbase + n;
                    hbuf[(1 - par) * (64 * 512) + b * 512 + j] = f2bf(h);
                    if (h1out) h1out[(size_t)(b * 512 + tt) * 512 + j] = f2bf(h);
                    if (fout) fout[(size_t)(b * 512 + tt) * 1024 + j] = h;
                }
            }
            __threadfence(); // publish this wave's h stores agent-wide
        }
        __syncthreads();
        if (tid == 0) {
            __hip_atomic_fetch_add(ctrg + t, 1u, __ATOMIC_RELEASE, __HIP_MEMORY_SCOPE_AGENT);
            while (__hip_atomic_load(ctrg + t, __ATOMIC_RELAXED, __HIP_MEMORY_SCOPE_AGENT) < 64u) {}
        }
        __syncthreads();
        __threadfence(); // acquire side: invalidate before reading peers' h
    }
}

// ---------------- LayerNorm(concat) + residual, in-place on d_out ----------------
__global__ __launch_bounds__(256) void ln_res(float* __restrict__ out,
                                              const float* __restrict__ x,
                                              const float* __restrict__ gamma,
                                              const float* __restrict__ beta) {
    int row = blockIdx.x;
    int tid = threadIdx.x, lane = tid & 63, wv = tid >> 6;
    const float4 hv = ((const float4*)(out + (size_t)row * 1024))[tid];
    const float4 xv = ((const float4*)(x + (size_t)row * 1024))[tid];
    float s = hv.x + hv.y + hv.z + hv.w;
    float ss = hv.x * hv.x + hv.y * hv.y + hv.z * hv.z + hv.w * hv.w;
    for (int o = 32; o > 0; o >>= 1) {
        s += __shfl_down(s, o);
        ss += __shfl_down(ss, o);
    }
    __shared__ float as_[4], bs_[4];
    if (lane == 0) { as_[wv] = s; bs_[wv] = ss; }
    __syncthreads();
    s = as_[0] + as_[1] + as_[2] + as_[3];
    ss = bs_[0] + bs_[1] + bs_[2] + bs_[3];
    float mu = s * (1.f / 1024.f);
    float var = ss * (1.f / 1024.f) - mu * mu;
    float rs = rsqrtf(var + 1e-6f);
    float4 gv = ((const float4*)gamma)[tid];
    float4 bv = ((const float4*)beta)[tid];
    float4 o4;
    o4.x = xv.x + (hv.x - mu) * rs * gv.x + bv.x;
    o4.y = xv.y + (hv.y - mu) * rs * gv.y + bv.y;
    o4.z = xv.z + (hv.z - mu) * rs * gv.z + bv.z;
    o4.w = xv.w + (hv.w - mu) * rs * gv.w + bv.w;
    ((float4*)(out + (size_t)row * 1024))[tid] = o4;
}

extern "C" void kernel_launch(void* const* d_in, const int* in_sizes, int n_in,
                              void* d_out, int out_size, void* d_ws, size_t ws_size,
                              hipStream_t stream) {
    const float* x = (const float*)d_in[0];
    const float* W1 = (const float*)d_in[1];
    const float* U1 = (const float*)d_in[2];
    const float* b1 = (const float*)d_in[3];
    const float* Wf = (const float*)d_in[4];
    const float* Uf = (const float*)d_in[5];
    const float* bfv = (const float*)d_in[6];
    const float* Wb = (const float*)d_in[7];
    const float* Ub = (const float*)d_in[8];
    const float* bbv = (const float*)d_in[9];
    const float* gamma = (const float*)d_in[10];
    const float* beta = (const float*)d_in[11];
    float* out = (float*)d_out;

    char* ws = (char*)d_ws;
    size_t off = 0;
    auto alloc = [&](size_t bytes) -> void* {
        void* p = ws + off;
        off += (bytes + 255) & ~(size_t)255;
        return p;
    };
    u16* xwA = (u16*)alloc(64ull * 512 * 2048 * 2); // xw1, later xwb
    u16* xwB = (u16*)alloc(64ull * 512 * 2048 * 2); // xwf
    u16* h1  = (u16*)alloc(64ull * 512 * 512 * 2);
    u16* xb  = (u16*)alloc(64ull * 512 * 1024 * 2);
    u16* W1t = (u16*)alloc(2048ull * 1024 * 2);
    u16* Wft = (u16*)alloc(2048ull * 512 * 2);
    u16* Wbt = (u16*)alloc(2048ull * 512 * 2);
    u16* U1t = (u16*)alloc(2048ull * 512 * 2);
    u16* Uft = (u16*)alloc(2048ull * 512 * 2);
    u16* Ubt = (u16*)alloc(2048ull * 512 * 2);
    const size_t HB = 2ull * 64 * 512 * 2;  // 131072 B per hbuf
    const size_t CT = 4ull * 512 * 4;       // 8192 B per counter set
    char* sync0 = (char*)alloc(3 * (HB + CT));

    u16* hb0 = (u16*)(sync0);
    u32* c0 = (u32*)(sync0 + HB);
    u16* hb1 = (u16*)(sync0 + (HB + CT));
    u32* c1 = (u32*)(sync0 + (HB + CT) + HB);
    u16* hb2 = (u16*)(sync0 + 2 * (HB + CT));
    u32* c2 = (u32*)(sync0 + 2 * (HB + CT) + HB);

    // zero h-broadcast buffers + barrier counters (re-poisoned each call)
    hipMemsetAsync(sync0, 0, 3 * (HB + CT), stream);

    // prep: casts + weight transposes
    cast_f32_bf16<<<32768, 256, 0, stream>>>(x, xb, 8388608);
    dim3 tb(32, 8);
    transpose_cast<<<dim3(64, 32), tb, 0, stream>>>(W1, W1t, 1024);
    transpose_cast<<<dim3(64, 16), tb, 0, stream>>>(U1, U1t, 512);
    transpose_cast<<<dim3(64, 16), tb, 0, stream>>>(Wf, Wft, 512);
    transpose_cast<<<dim3(64, 16), tb, 0, stream>>>(Uf, Uft, 512);
    transpose_cast<<<dim3(64, 16), tb, 0, stream>>>(Wb, Wbt, 512);
    transpose_cast<<<dim3(64, 16), tb, 0, stream>>>(Ub, Ubt, 512);

    // xw1 = x @ W1 + b1
    gemm_bt<<<dim3(16, 256), 256, 0, stream>>>(xb, W1t, b1, xwA, 32768, 2048, 1024);
    // LSTM1 -> h1 (bf16)
    lstm_rec<<<256, 256, 0, stream>>>(xwA, U1t, hb0, c0, h1, nullptr, 0);
    // xwf = h1 @ Wf + bf ; xwb = h1 @ Wb + bb (xwA reused)
    gemm_bt<<<dim3(16, 256), 256, 0, stream>>>(h1, Wft, bfv, xwB, 32768, 2048, 512);
    gemm_bt<<<dim3(16, 256), 256, 0, stream>>>(h1, Wbt, bbv, xwA, 32768, 2048, 512);
    // forward LSTM -> d_out[:, :, 0:512]
    lstm_rec<<<256, 256, 0, stream>>>(xwB, Uft, hb1, c1, nullptr, out, 0);
    // backward LSTM -> d_out[:, :, 512:1024]
    lstm_rec<<<256, 256, 0, stream>>>(xwA, Ubt, hb2, c2, nullptr, out + 512, 1);
    // LayerNorm + residual, in place
    ln_res<<<32768, 256, 0, stream>>>(out, x, gamma, beta);
}

// Round 2
// 5726.777 us; speedup vs baseline: 8.7876x; 8.7876x over previous
//
#include <hip/hip_runtime.h>
#include <stdint.h>

typedef __attribute__((ext_vector_type(8))) short short8;
typedef __attribute__((ext_vector_type(4))) float f32x4;
typedef unsigned short u16;
typedef unsigned int u32;
typedef unsigned long long u64;

__device__ __forceinline__ float bf2f(u16 v) {
    u32 t = ((u32)v) << 16; float f; __builtin_memcpy(&f, &t, 4); return f;
}
__device__ __forceinline__ u16 f2bf(float f) {
    u32 t; __builtin_memcpy(&t, &f, 4);
    return (u16)((t + 0x7FFFu + ((t >> 16) & 1u)) >> 16);
}

// ---------------- cast x (f32 -> bf16), 4 elems/thread ----------------
__global__ __launch_bounds__(256) void cast_f32_bf16(const float* __restrict__ in,
                                                     u16* __restrict__ out, int n4) {
    int i = blockIdx.x * 256 + threadIdx.x;
    if (i < n4) {
        float4 v = ((const float4*)in)[i];
        uint2 pk;
        pk.x = (u32)f2bf(v.x) | ((u32)f2bf(v.y) << 16);
        pk.y = (u32)f2bf(v.z) | ((u32)f2bf(v.w) << 16);
        ((uint2*)out)[i] = pk;
    }
}

// ---------- transpose + cast: in f32 [K][2048] -> out bf16 [2048][K] ----------
__global__ void transpose_cast(const float* __restrict__ in, u16* __restrict__ out, int K) {
    __shared__ float tile[32][33];
    int n0 = blockIdx.x * 32, k0 = blockIdx.y * 32;
    int tx = threadIdx.x, ty = threadIdx.y; // block (32,8)
    for (int i = 0; i < 4; i++)
        tile[ty + i * 8][tx] = in[(size_t)(k0 + ty + i * 8) * 2048 + n0 + tx];
    __syncthreads();
    for (int i = 0; i < 4; i++)
        out[(size_t)(n0 + ty + i * 8) * K + k0 + tx] = f2bf(tile[tx][ty + i * 8]);
}

// ------- bf16 MFMA GEMM: C[t*64+b, col] = (A[M,K] @ Bt[N,K]^T + bias), M rows are b*512+t -------
// Output is written TIME-MAJOR: logical row (b*512+t) stored at row (t*64+b). N=2048 assumed for C.
__global__ __launch_bounds__(256) void gemm_bt(const u16* __restrict__ A,
                                               const u16* __restrict__ Bt,
                                               const float* __restrict__ bias,
                                               u16* __restrict__ C,
                                               int M, int N, int K) {
    __shared__ u16 As[128 * 40];
    __shared__ u16 Bs[128 * 40];
    int bm = blockIdx.y, bn = blockIdx.x;
    int tid = threadIdx.x, lane = tid & 63, wv = tid >> 6;
    int n = lane & 15, q = lane >> 4;
    int wm = wv & 1, wn = wv >> 1;
    f32x4 acc[4][4] = {};
    int rowA0 = bm * 128, rowB0 = bn * 128;
    for (int kt = 0; kt < K; kt += 32) {
        uint4 va[2], vb[2];
        #pragma unroll
        for (int s = 0; s < 2; s++) {
            int slot = tid + s * 256;
            int row = slot >> 2, ko = (slot & 3) * 8;
            va[s] = *(const uint4*)(A + (size_t)(rowA0 + row) * K + kt + ko);
            vb[s] = *(const uint4*)(Bt + (size_t)(rowB0 + row) * K + kt + ko);
        }
        __syncthreads();
        #pragma unroll
        for (int s = 0; s < 2; s++) {
            int slot = tid + s * 256;
            int row = slot >> 2, ko = (slot & 3) * 8;
            *(uint4*)(As + row * 40 + ko) = va[s];
            *(uint4*)(Bs + row * 40 + ko) = vb[s];
        }
        __syncthreads();
        short8 af[4], bfr[4];
        #pragma unroll
        for (int i = 0; i < 4; i++)
            af[i] = *(const short8*)(As + (wm * 64 + i * 16 + n) * 40 + q * 8);
        #pragma unroll
        for (int j = 0; j < 4; j++)
            bfr[j] = *(const short8*)(Bs + (wn * 64 + j * 16 + n) * 40 + q * 8);
        #pragma unroll
        for (int i = 0; i < 4; i++)
            #pragma unroll
            for (int j = 0; j < 4; j++)
                acc[i][j] = __builtin_amdgcn_mfma_f32_16x16x32_bf16(af[i], bfr[j], acc[i][j], 0, 0, 0);
    }
    #pragma unroll
    for (int j = 0; j < 4; j++) {
        int col = bn * 128 + wn * 64 + j * 16 + n;
        float bv = bias[col];
        #pragma unroll
        for (int i = 0; i < 4; i++) {
            int row0 = bm * 128 + wm * 64 + i * 16 + q * 4;
            #pragma unroll
            for (int r = 0; r < 4; r++) {
                int row = row0 + r;
                int b = row >> 9, t = row & 511;
                C[((size_t)t * 64 + b) * N + col] = f2bf(acc[i][j][r] + bv);
            }
        }
    }
}

// ---------------- persistent LSTM recurrence, XCD-local sync groups ----------------
// Grid 256 (single layer) or 512 (dual: fwd half + bwd half). Per 256-block half:
// group g = bid&7 (one XCD under round-robin) owns batches [g*8, +8); rank rk=bid>>3
// owns j-cols [rk*16, +16). Wave wv = gate (i,f,g,o). U frags register-resident.
// Cross-WG h exchange via per-access agent-coherent loads/stores (NO cache-wide
// fences -- the round-1 killer was per-step buffer_inv/wbl2 from __threadfence).
__global__ __launch_bounds__(256) void lstm_rec(
    const u16* __restrict__ xw0, const u16* __restrict__ Ut0, u16* __restrict__ hbA,
    u32* __restrict__ ctrA, u16* __restrict__ h1oA, float* __restrict__ foA,
    const u16* __restrict__ xw1, const u16* __restrict__ Ut1, u16* __restrict__ hbB,
    u32* __restrict__ ctrB, u16* __restrict__ h1oB, float* __restrict__ foB) {
    __shared__ u16 hs[16 * 520];      // staged h tile: rows 0-7 live, 8-15 zero
    __shared__ float zbuf[4][8 * 17]; // gate exchange

    int dir = blockIdx.x >> 8;
    const u16* xw = dir ? xw1 : xw0;
    const u16* Ut = dir ? Ut1 : Ut0;
    u16* hbuf = dir ? hbB : hbA;
    u32* ctr = dir ? ctrB : ctrA;
    u16* h1out = dir ? h1oB : h1oA;
    float* fout = dir ? foB : foA;
    int reverse = dir; // layer2 half B is the backward direction; layer1 uses half A only

    int bid = blockIdx.x & 255;
    int g = bid & 7;    // batch group -> XCD under round-robin placement
    int rk = bid >> 3;  // 0..31
    int jbase = rk * 16;
    int b0 = g * 8;
    int tid = threadIdx.x, lane = tid & 63, wv = tid >> 6;
    int n = lane & 15, q = lane >> 4;
    int gcol = wv * 512 + jbase + n; // z column: gate wv, j = jbase+n

    // register-resident U^T fragments: full K=512 (16 steps of 32)
    short8 Breg[16];
    #pragma unroll
    for (int s = 0; s < 16; s++)
        Breg[s] = *(const short8*)(Ut + (size_t)gcol * 512 + s * 32 + q * 8);

    // zero LDS (rows 8-15 of hs must stay zero: they feed MFMA garbage rows)
    for (int i = tid; i < 16 * 520 / 2; i += 256) ((u32*)hs)[i] = 0;
    __syncthreads();

    float cst = 0.f;              // c-state: owned by threads tid<128 (8b x 16j)
    int bl = tid >> 4, jj = tid & 15;
    u32* ctrg = ctr + g * 512;
    int srow = tid >> 5;          // staging: 8 rows x 32 threads
    int soff = (tid & 31) * 16;

    float xwv[4];
    {
        int tt0 = reverse ? 511 : 0;
        #pragma unroll
        for (int rr = 0; rr < 4; rr++) {
            int row = q * 4 + rr;
            xwv[rr] = (row < 8) ? bf2f(xw[((size_t)tt0 * 64 + b0 + row) * 2048 + gcol]) : 0.f;
        }
    }

    for (int t = 0; t < 512; t++) {
        int tt = reverse ? (511 - t) : t;
        int par = t & 1;

        // stage h_{t-1}[8][512] via agent-coherent 8B loads (bypass stale L2)
        {
            u64* src = (u64*)(hbuf + par * (64 * 512) + (size_t)(b0 + srow) * 512 + soff);
            u64 v[4];
            #pragma unroll
            for (int k = 0; k < 4; k++)
                v[k] = __hip_atomic_load(src + k, __ATOMIC_RELAXED, __HIP_MEMORY_SCOPE_AGENT);
            u64* dst = (u64*)(hs + srow * 520 + soff);
            #pragma unroll
            for (int k = 0; k < 4; k++) dst[k] = v[k];
        }
        __syncthreads();

        f32x4 acc = {xwv[0], xwv[1], xwv[2], xwv[3]};
        #pragma unroll
        for (int s = 0; s < 16; s++) {
            short8 a = *(const short8*)(hs + n * 520 + s * 32 + q * 8);
            acc = __builtin_amdgcn_mfma_f32_16x16x32_bf16(a, Breg[s], acc, 0, 0, 0);
        }

        // prefetch next step's xw (overlaps the exchange/barrier latency)
        if (t < 511) {
            int ttn = reverse ? (511 - (t + 1)) : (t + 1);
            #pragma unroll
            for (int rr = 0; rr < 4; rr++) {
                int row = q * 4 + rr;
                if (row < 8) xwv[rr] = bf2f(xw[((size_t)ttn * 64 + b0 + row) * 2048 + gcol]);
            }
        }

        // publish gate partials (valid rows 0-7) to LDS
        if (q < 2) {
            #pragma unroll
            for (int rr = 0; rr < 4; rr++)
                zbuf[wv][(q * 4 + rr) * 17 + n] = acc[rr];
        }
        __syncthreads();

        if (tid < 128) {
            float zi = zbuf[0][bl * 17 + jj];
            float zf = zbuf[1][bl * 17 + jj];
            float zg = zbuf[2][bl * 17 + jj];
            float zo = zbuf[3][bl * 17 + jj];
            float si = 1.f / (1.f + __expf(-zi));
            float sf = 1.f / (1.f + __expf(-zf));
            float so = 1.f / (1.f + __expf(-zo));
            float gg = zg > 0.f ? zg : 0.f;
            cst = sf * cst + si * gg;
            float h = so * (cst > 0.f ? cst : 0.f);
            int b = b0 + bl;
            int j = jbase + jj;
            u16 hv = f2bf(h);
            int partner = __shfl_xor((int)hv, 1);
            if ((jj & 1) == 0) { // packed 4B agent-coherent (write-through) h store
                u32 pk = (u32)hv | ((u32)partner << 16);
                u32* dst = (u32*)(hbuf + (1 - par) * (64 * 512) + (size_t)b * 512 + j);
                __hip_atomic_store(dst, pk, __ATOMIC_RELAXED, __HIP_MEMORY_SCOPE_AGENT);
            }
            if (h1out) h1out[((size_t)b * 512 + tt) * 512 + j] = hv;
            if (fout) fout[((size_t)b * 512 + tt) * 1024 + j] = h;
        }
        // order: h stores reach the coherence point before the arrival increment
        asm volatile("s_waitcnt vmcnt(0)" ::: "memory");
        __syncthreads();
        if (tid == 0) {
            __hip_atomic_fetch_add(ctrg + t, 1u, __ATOMIC_RELAXED, __HIP_MEMORY_SCOPE_AGENT);
            while (__hip_atomic_load(ctrg + t, __ATOMIC_RELAXED, __HIP_MEMORY_SCOPE_AGENT) < 32u)
                __builtin_amdgcn_s_sleep(1);
        }
        __syncthreads();
    }
}

// ---------------- LayerNorm(concat) + residual, in-place on d_out ----------------
__global__ __launch_bounds__(256) void ln_res(float* __restrict__ out,
                                              const float* __restrict__ x,
                                              const float* __restrict__ gamma,
                                              const float* __restrict__ beta) {
    int row = blockIdx.x;
    int tid = threadIdx.x, lane = tid & 63, wv = tid >> 6;
    const float4 hv = ((const float4*)(out + (size_t)row * 1024))[tid];
    const float4 xv = ((const float4*)(x + (size_t)row * 1024))[tid];
    float s = hv.x + hv.y + hv.z + hv.w;
    float ss = hv.x * hv.x + hv.y * hv.y + hv.z * hv.z + hv.w * hv.w;
    for (int o = 32; o > 0; o >>= 1) {
        s += __shfl_down(s, o);
        ss += __shfl_down(ss, o);
    }
    __shared__ float as_[4], bs_[4];
    if (lane == 0) { as_[wv] = s; bs_[wv] = ss; }
    __syncthreads();
    s = as_[0] + as_[1] + as_[2] + as_[3];
    ss = bs_[0] + bs_[1] + bs_[2] + bs_[3];
    float mu = s * (1.f / 1024.f);
    float var = ss * (1.f / 1024.f) - mu * mu;
    float rs = rsqrtf(var + 1e-6f);
    float4 gv = ((const float4*)gamma)[tid];
    float4 bv = ((const float4*)beta)[tid];
    float4 o4;
    o4.x = xv.x + (hv.x - mu) * rs * gv.x + bv.x;
    o4.y = xv.y + (hv.y - mu) * rs * gv.y + bv.y;
    o4.z = xv.z + (hv.z - mu) * rs * gv.z + bv.z;
    o4.w = xv.w + (hv.w - mu) * rs * gv.w + bv.w;
    ((float4*)(out + (size_t)row * 1024))[tid] = o4;
}

extern "C" void kernel_launch(void* const* d_in, const int* in_sizes, int n_in,
                              void* d_out, int out_size, void* d_ws, size_t ws_size,
                              hipStream_t stream) {
    const float* x = (const float*)d_in[0];
    const float* W1 = (const float*)d_in[1];
    const float* U1 = (const float*)d_in[2];
    const float* b1 = (const float*)d_in[3];
    const float* Wf = (const float*)d_in[4];
    const float* Uf = (const float*)d_in[5];
    const float* bfv = (const float*)d_in[6];
    const float* Wb = (const float*)d_in[7];
    const float* Ub = (const float*)d_in[8];
    const float* bbv = (const float*)d_in[9];
    const float* gamma = (const float*)d_in[10];
    const float* beta = (const float*)d_in[11];
    float* out = (float*)d_out;

    char* ws = (char*)d_ws;
    size_t off = 0;
    auto alloc = [&](size_t bytes) -> void* {
        void* p = ws + off;
        off += (bytes + 255) & ~(size_t)255;
        return p;
    };
    u16* xwA = (u16*)alloc(64ull * 512 * 2048 * 2); // xw1, later xwb (time-major)
    u16* xwB = (u16*)alloc(64ull * 512 * 2048 * 2); // xwf (time-major)
    u16* h1  = (u16*)alloc(64ull * 512 * 512 * 2);  // [b*512+t][512]
    u16* xb  = (u16*)alloc(64ull * 512 * 1024 * 2);
    u16* W1t = (u16*)alloc(2048ull * 1024 * 2);
    u16* Wft = (u16*)alloc(2048ull * 512 * 2);
    u16* Wbt = (u16*)alloc(2048ull * 512 * 2);
    u16* U1t = (u16*)alloc(2048ull * 512 * 2);
    u16* Uft = (u16*)alloc(2048ull * 512 * 2);
    u16* Ubt = (u16*)alloc(2048ull * 512 * 2);
    const size_t HB = 2ull * 64 * 512 * 2; // double-buffered h broadcast
    const size_t CT = 8ull * 512 * 4;      // 8 groups x 512 step counters
    char* sync0 = (char*)alloc(3 * (HB + CT));

    u16* hb0 = (u16*)(sync0);
    u32* c0 = (u32*)(sync0 + HB);
    u16* hb1 = (u16*)(sync0 + (HB + CT));
    u32* c1 = (u32*)(sync0 + (HB + CT) + HB);
    u16* hb2 = (u16*)(sync0 + 2 * (HB + CT));
    u32* c2 = (u32*)(sync0 + 2 * (HB + CT) + HB);

    hipMemsetAsync(sync0, 0, 3 * (HB + CT), stream);

    cast_f32_bf16<<<32768, 256, 0, stream>>>(x, xb, 8388608);
    dim3 tb(32, 8);
    transpose_cast<<<dim3(64, 32), tb, 0, stream>>>(W1, W1t, 1024);
    transpose_cast<<<dim3(64, 16), tb, 0, stream>>>(U1, U1t, 512);
    transpose_cast<<<dim3(64, 16), tb, 0, stream>>>(Wf, Wft, 512);
    transpose_cast<<<dim3(64, 16), tb, 0, stream>>>(Uf, Uft, 512);
    transpose_cast<<<dim3(64, 16), tb, 0, stream>>>(Wb, Wbt, 512);
    transpose_cast<<<dim3(64, 16), tb, 0, stream>>>(Ub, Ubt, 512);

    // xw1 = x @ W1 + b1 (time-major out)
    gemm_bt<<<dim3(16, 256), 256, 0, stream>>>(xb, W1t, b1, xwA, 32768, 2048, 1024);
    // LSTM1 -> h1
    lstm_rec<<<256, 256, 0, stream>>>(xwA, U1t, hb0, c0, h1, nullptr,
                                      xwA, U1t, hb0, c0, nullptr, nullptr);
    // xwf = h1 @ Wf + bf ; xwb = h1 @ Wb + bb
    gemm_bt<<<dim3(16, 256), 256, 0, stream>>>(h1, Wft, bfv, xwB, 32768, 2048, 512);
    gemm_bt<<<dim3(16, 256), 256, 0, stream>>>(h1, Wbt, bbv, xwA, 32768, 2048, 512);
    // fwd (half A) + bwd (half B) LSTMs concurrently
    lstm_rec<<<512, 256, 0, stream>>>(xwB, Uft, hb1, c1, nullptr, out,
                                      xwA, Ubt, hb2, c2, nullptr, out + 512);
    // LayerNorm + residual, in place
    ln_res<<<32768, 256, 0, stream>>>(out, x, gamma, beta);
}